// Round 1
// baseline (220.501 us; speedup 1.0000x reference)
//
#include <hip/hip_runtime.h>

#define G_ 4
#define B_ 4
#define L_ 512
#define C_ 768
#define NH_ 12
#define DH_ 64
#define T_ 2048  // B_*L_

typedef __bf16 bf16x8 __attribute__((ext_vector_type(8)));
typedef float f32x4 __attribute__((ext_vector_type(4)));
typedef unsigned int u32x4 __attribute__((ext_vector_type(4)));
typedef unsigned short u16;
typedef unsigned short u16x4 __attribute__((ext_vector_type(4)));

__device__ __forceinline__ u16 f2bf(float x) {
    unsigned u = __builtin_bit_cast(unsigned, x);
    u = (u + 0x7FFFu + ((u >> 16) & 1u)) >> 16;
    return (u16)u;
}

// ---------------- kernel 1: hs fp32 -> bf16 ----------------
__global__ void k_convert(const float* __restrict__ in, u16* __restrict__ out, int n4) {
    int i = blockIdx.x * blockDim.x + threadIdx.x;
    if (i >= n4) return;
    float4 v = reinterpret_cast<const float4*>(in)[i];
    u16x4 o;
    o.x = f2bf(v.x); o.y = f2bf(v.y); o.z = f2bf(v.z); o.w = f2bf(v.w);
    reinterpret_cast<u16x4*>(out)[i] = o;
}

// ------- kernel 2: W fp32 [g][c][d] -> bf16 Wt [qkv][g][d][c] -------
__global__ void k_transpose(const float* __restrict__ wq, const float* __restrict__ wk,
                            const float* __restrict__ wv, u16* __restrict__ wt) {
    __shared__ u16 tile[32][33];
    int qkv = blockIdx.z >> 2, g = blockIdx.z & 3;
    const float* W = (qkv == 0 ? wq : qkv == 1 ? wk : wv) + g * (C_ * C_);
    u16* O = wt + blockIdx.z * (C_ * C_);
    int d0 = blockIdx.x * 32, c0 = blockIdx.y * 32;
    int tx = threadIdx.x, ty = threadIdx.y;
#pragma unroll
    for (int j = 0; j < 4; j++)
        tile[ty + 8 * j][tx] = f2bf(W[(c0 + ty + 8 * j) * C_ + d0 + tx]);
    __syncthreads();
#pragma unroll
    for (int j = 0; j < 4; j++)
        O[(d0 + ty + 8 * j) * C_ + c0 + tx] = tile[tx][ty + 8 * j];
}

// ------- kernel 3: QKV GEMM, bf16 MFMA, out[qkv][g][t][d] bf16 -------
#define BM 128
#define BN 128
#define BK 64
#define LDK 72  // padded LDS stride (bf16 elems): 144B, 16B-aligned, bank-rotating

__global__ __launch_bounds__(256) void k_qkv_gemm(
    const u16* __restrict__ hsb, const u16* __restrict__ wt,
    const float* __restrict__ qb, const float* __restrict__ kb,
    const float* __restrict__ vb, u16* __restrict__ qkvout) {
    __shared__ u16 Asm[BM * LDK];
    __shared__ u16 Bsm[BN * LDK];
    int qkv = blockIdx.z >> 2, g = blockIdx.z & 3;
    int n0 = blockIdx.x * BN, m0 = blockIdx.y * BM;
    const u16* Ag = hsb + g * (T_ * C_);
    const u16* Bg = wt + blockIdx.z * (C_ * C_);
    const float* bias = (qkv == 0 ? qb : qkv == 1 ? kb : vb) + g * C_;
    u16* Og = qkvout + qkv * (G_ * T_ * C_) + g * (T_ * C_);

    int tid = threadIdx.x;
    int lane = tid & 63, w = tid >> 6;
    int wm = (w >> 1) * 64, wn = (w & 1) * 64;
    int l15 = lane & 15, l4 = lane >> 4;

    f32x4 acc[4][4];
#pragma unroll
    for (int a = 0; a < 4; a++)
#pragma unroll
        for (int b = 0; b < 4; b++) acc[a][b] = (f32x4){0.f, 0.f, 0.f, 0.f};

    for (int k0 = 0; k0 < C_; k0 += BK) {
#pragma unroll
        for (int it = 0; it < 4; it++) {
            int ch = tid + it * 256;
            int r = ch >> 3, c8 = ch & 7;
            u32x4 a = *reinterpret_cast<const u32x4*>(Ag + (m0 + r) * C_ + k0 + c8 * 8);
            *reinterpret_cast<u32x4*>(&Asm[r * LDK + c8 * 8]) = a;
            u32x4 b = *reinterpret_cast<const u32x4*>(Bg + (n0 + r) * C_ + k0 + c8 * 8);
            *reinterpret_cast<u32x4*>(&Bsm[r * LDK + c8 * 8]) = b;
        }
        __syncthreads();
#pragma unroll
        for (int kk = 0; kk < 2; kk++) {
            bf16x8 af[4], bfr[4];
#pragma unroll
            for (int mi = 0; mi < 4; mi++)
                af[mi] = __builtin_bit_cast(bf16x8, *reinterpret_cast<const u32x4*>(
                             &Asm[(wm + mi * 16 + l15) * LDK + kk * 32 + l4 * 8]));
#pragma unroll
            for (int ni = 0; ni < 4; ni++)
                bfr[ni] = __builtin_bit_cast(bf16x8, *reinterpret_cast<const u32x4*>(
                              &Bsm[(wn + ni * 16 + l15) * LDK + kk * 32 + l4 * 8]));
#pragma unroll
            for (int mi = 0; mi < 4; mi++)
#pragma unroll
                for (int ni = 0; ni < 4; ni++)
                    acc[mi][ni] = __builtin_amdgcn_mfma_f32_16x16x32_bf16(
                        af[mi], bfr[ni], acc[mi][ni], 0, 0, 0);
        }
        __syncthreads();
    }
#pragma unroll
    for (int ni = 0; ni < 4; ni++) {
        int col = n0 + wn + ni * 16 + l15;
        float bv = bias[col];
#pragma unroll
        for (int mi = 0; mi < 4; mi++) {
#pragma unroll
            for (int i = 0; i < 4; i++) {
                int row = m0 + wm + mi * 16 + l4 * 4 + i;
                Og[row * C_ + col] = f2bf(acc[mi][ni][i] + bv);
            }
        }
    }
}

// ------- kernel 4: fused flash attention -------
#define LDA 72
#define SCALE 0.125f

__global__ __launch_bounds__(256) void k_attn(
    const u16* __restrict__ qkv, const float* __restrict__ mask,
    float* __restrict__ out) {
    __shared__ u16 Ksm[64 * LDA];   // [k'][d]
    __shared__ u16 Vsm[64 * LDA];   // transposed: [d][k']
    __shared__ u16 Psm[64 * LDA];   // per-wave strips [qrow][k']
    __shared__ float msk[L_];

    int qt = blockIdx.x, h = blockIdx.y, gb = blockIdx.z;
    int g = gb >> 2, b = gb & 3;
    int q0 = qt * 64;
    int tid = threadIdx.x, lane = tid & 63, w = tid >> 6;
    int l15 = lane & 15, l4 = lane >> 4;

    const int QKVSZ = G_ * T_ * C_;
    const u16* Qg = qkv + g * (T_ * C_) + (b * L_) * C_ + h * DH_;
    const u16* Kg = qkv + QKVSZ + g * (T_ * C_) + (b * L_) * C_ + h * DH_;
    const u16* Vg = qkv + 2 * QKVSZ + g * (T_ * C_) + (b * L_) * C_ + h * DH_;

    for (int i = tid; i < L_; i += 256) msk[i] = mask[(g * B_ + b) * L_ + i];

    bf16x8 qf[2];
#pragma unroll
    for (int kk = 0; kk < 2; kk++)
        qf[kk] = __builtin_bit_cast(bf16x8, *reinterpret_cast<const u32x4*>(
                     Qg + (q0 + w * 16 + l15) * C_ + kk * 32 + l4 * 8));

    float mrun[4], lrun[4];
    f32x4 accO[4];
#pragma unroll
    for (int i = 0; i < 4; i++) { mrun[i] = -1e30f; lrun[i] = 0.f; }
#pragma unroll
    for (int df = 0; df < 4; df++) accO[df] = (f32x4){0.f, 0.f, 0.f, 0.f};

    int r = tid >> 2, c8a = tid & 3;
    for (int kt = 0; kt < 8; kt++) {
        int krow0 = kt * 64;
        __syncthreads();  // protect prior-iter LDS reads (and mask stores on iter 0)
#pragma unroll
        for (int half = 0; half < 2; half++) {
            int c8 = c8a + half * 4;
            u32x4 kv = *reinterpret_cast<const u32x4*>(Kg + (krow0 + r) * C_ + c8 * 8);
            *reinterpret_cast<u32x4*>(&Ksm[r * LDA + c8 * 8]) = kv;
            u32x4 vv = *reinterpret_cast<const u32x4*>(Vg + (krow0 + r) * C_ + c8 * 8);
            union { u32x4 q; u16 u[8]; } uu; uu.q = vv;
#pragma unroll
            for (int j = 0; j < 8; j++)
                Vsm[(c8 * 8 + j) * LDA + r] = uu.u[j];
        }
        __syncthreads();

        f32x4 s[4];
#pragma unroll
        for (int nf = 0; nf < 4; nf++) s[nf] = (f32x4){0.f, 0.f, 0.f, 0.f};
#pragma unroll
        for (int kk = 0; kk < 2; kk++) {
#pragma unroll
            for (int nf = 0; nf < 4; nf++) {
                bf16x8 kf = __builtin_bit_cast(bf16x8, *reinterpret_cast<const u32x4*>(
                                &Ksm[(nf * 16 + l15) * LDA + kk * 32 + l4 * 8]));
                s[nf] = __builtin_amdgcn_mfma_f32_16x16x32_bf16(qf[kk], kf, s[nf], 0, 0, 0);
            }
        }

        float mv[4];
#pragma unroll
        for (int nf = 0; nf < 4; nf++) mv[nf] = msk[krow0 + nf * 16 + l15];

        float p[4][4];
#pragma unroll
        for (int i = 0; i < 4; i++) {
            float sv[4];
#pragma unroll
            for (int nf = 0; nf < 4; nf++) sv[nf] = fmaf(s[nf][i], SCALE, mv[nf]);
            float mx = fmaxf(fmaxf(sv[0], sv[1]), fmaxf(sv[2], sv[3]));
            mx = fmaxf(mx, __shfl_xor(mx, 1));
            mx = fmaxf(mx, __shfl_xor(mx, 2));
            mx = fmaxf(mx, __shfl_xor(mx, 4));
            mx = fmaxf(mx, __shfl_xor(mx, 8));
            float mn = fmaxf(mrun[i], mx);
            float alpha = __expf(mrun[i] - mn);
            mrun[i] = mn;
            float rs = 0.f;
#pragma unroll
            for (int nf = 0; nf < 4; nf++) { p[nf][i] = __expf(sv[nf] - mn); rs += p[nf][i]; }
            rs += __shfl_xor(rs, 1);
            rs += __shfl_xor(rs, 2);
            rs += __shfl_xor(rs, 4);
            rs += __shfl_xor(rs, 8);
            lrun[i] = lrun[i] * alpha + rs;
#pragma unroll
            for (int df = 0; df < 4; df++) accO[df][i] *= alpha;
        }

#pragma unroll
        for (int nf = 0; nf < 4; nf++)
#pragma unroll
            for (int i = 0; i < 4; i++)
                Psm[(w * 16 + l4 * 4 + i) * LDA + nf * 16 + l15] = f2bf(p[nf][i]);

#pragma unroll
        for (int kk = 0; kk < 2; kk++) {
            bf16x8 pf = __builtin_bit_cast(bf16x8, *reinterpret_cast<const u32x4*>(
                            &Psm[(w * 16 + l15) * LDA + kk * 32 + l4 * 8]));
#pragma unroll
            for (int df = 0; df < 4; df++) {
                bf16x8 vf = __builtin_bit_cast(bf16x8, *reinterpret_cast<const u32x4*>(
                                &Vsm[(df * 16 + l15) * LDA + kk * 32 + l4 * 8]));
                accO[df] = __builtin_amdgcn_mfma_f32_16x16x32_bf16(pf, vf, accO[df], 0, 0, 0);
            }
        }
    }

#pragma unroll
    for (int i = 0; i < 4; i++) {
        float inv = 1.0f / lrun[i];
        int row = q0 + w * 16 + l4 * 4 + i;
#pragma unroll
        for (int df = 0; df < 4; df++)
            out[((g * B_ + b) * L_ + row) * C_ + h * DH_ + df * 16 + l15] =
                accO[df][i] * inv;
    }
}

// ---------------- host launcher ----------------
extern "C" void kernel_launch(void* const* d_in, const int* in_sizes, int n_in,
                              void* d_out, int out_size, void* d_ws, size_t ws_size,
                              hipStream_t stream) {
    (void)in_sizes; (void)n_in; (void)out_size; (void)ws_size;
    const float* hs = (const float*)d_in[0];
    const float* mask = (const float*)d_in[1];
    const float* qw = (const float*)d_in[2];
    const float* qb = (const float*)d_in[3];
    const float* kw = (const float*)d_in[4];
    const float* kb = (const float*)d_in[5];
    const float* vw = (const float*)d_in[6];
    const float* vb = (const float*)d_in[7];
    float* out = (float*)d_out;

    char* ws = (char*)d_ws;
    const size_t OFF_WT = (size_t)G_ * T_ * C_ * 2;                  // 12,582,912
    const size_t OFF_QKV = OFF_WT + (size_t)3 * G_ * C_ * C_ * 2;    // +14,155,776
    u16* hsb = (u16*)ws;
    u16* wt = (u16*)(ws + OFF_WT);
    u16* qkvb = (u16*)(ws + OFF_QKV);

    int n4 = (G_ * T_ * C_) / 4;
    k_convert<<<(n4 + 255) / 256, 256, 0, stream>>>(hs, hsb, n4);
    k_transpose<<<dim3(C_ / 32, C_ / 32, 12), dim3(32, 8), 0, stream>>>(qw, kw, vw, wt);
    k_qkv_gemm<<<dim3(C_ / BN, T_ / BM, 12), 256, 0, stream>>>(hsb, wt, qb, kb, vb, qkvb);
    k_attn<<<dim3(L_ / 64, NH_, G_ * B_), 256, 0, stream>>>(qkvb, mask, out);
}